// Round 13
// baseline (126.919 us; speedup 1.0000x reference)
//
#include <hip/hip_runtime.h>

// Problem constants (match reference)
#define B 512
#define D 512
#define NC 100000
#define BETA 0.1f
#define MARGIN 50.0f
#define TPB 256
#define NFLOAT (NC * D)            // 51,200,000 floats in new_centers
// Aligned f4 groups of the OUT buffer: group g = out[4g..4g+4).
// Group 0 holds loss + centers[0..2] (patched scalar); groups [1, NG) are bulk.
// out[4g+0]=centers[4g-1]=src4[g-1].w ; out[4g+1..3]=src4[g].x/.y/.z
#define NG 12800000
// chunk boundaries over groups [1, NG), ~proportional to copy-worker counts 1536/1792/1536/1791
#define K0E 2954330
#define K1E 6401047
#define K2E 9355376

typedef float f4 __attribute__((ext_vector_type(4)));

// Copy out-groups [lo,hi): BOTH sides 16B-aligned. Each lane: 1 aligned f4 load,
// shfl_up for the previous group's .w (lane 0 patch-loads), aligned PLAIN f4 store
// (A/B vs R10: nontemporal dropped — suspect nt caps mixed-stream write BW).
// ALL loop conditions are wave-uniform, so every lane executes every __shfl_up
// in lockstep; loads clamped, stores predicated.
__device__ __forceinline__ void copy_groups(const f4* __restrict__ src4, f4* __restrict__ dst4,
                                            int lo, int hi, int widx, int wstride)
{
    const int lane = widx & 63;
    int g = lo + widx;
    for (; (g - lane) + 63 + 7 * wstride < hi; g += 8 * wstride) {
        f4 v[8];
        #pragma unroll
        for (int u = 0; u < 8; ++u) v[u] = src4[g + u * wstride];
        float pw[8];
        #pragma unroll
        for (int u = 0; u < 8; ++u) {
            pw[u] = __shfl_up(v[u].w, 1, 64);
            if (lane == 0) pw[u] = src4[g + u * wstride - 1].w;
        }
        #pragma unroll
        for (int u = 0; u < 8; ++u) {
            f4 o = { pw[u], v[u].x, v[u].y, v[u].z };
            dst4[g + u * wstride] = o;
        }
    }
    for (; (g - lane) < hi; g += wstride) {
        int gc = (g < hi) ? g : (hi - 1);
        f4 v = src4[gc];
        float pw = __shfl_up(v.w, 1, 64);
        if (lane == 0) pw = src4[gc - 1].w;
        if (g < hi) {
            f4 o = { pw, v.x, v.y, v.z };
            dst4[g] = o;
        }
    }
}

// ---- k0: blocks 0-511 gather cg + loss partial + winner; blocks 512-2047 copy chunk0 ----
__global__ __launch_bounds__(TPB) void k0_gather(
    const float* __restrict__ centers, const float* __restrict__ features,
    const int* __restrict__ labels, float* __restrict__ cgbuf,
    float* __restrict__ rowLoss, int* __restrict__ winner, float* __restrict__ outAll)
{
    const int b = blockIdx.x, t = threadIdx.x;
    if (b < B) {
        __shared__ float red[TPB];
        __shared__ int labs[B];
        __shared__ int wsh;
        labs[t] = labels[t]; labs[t + 256] = labels[t + 256];
        if (t == 0) wsh = 1;
        __syncthreads();
        const int i = b;
        const int li = labs[i];
        const float2* crow = (const float2*)(centers + (size_t)li * D);
        const float2* frow = (const float2*)(features + (size_t)i * D);
        float2 c = crow[t], f = frow[t];
        ((float2*)(cgbuf + (size_t)i * D))[t] = c;
        float dx = c.x - f.x, dy = c.y - f.y;
        red[t] = fminf(fmaxf(dx * dx, 1e-12f), 1e12f) + fminf(fmaxf(dy * dy, 1e-12f), 1e12f);
        for (int j = i + 1 + t; j < B; j += TPB)
            if (labs[j] == li) wsh = 0;           // benign race, same value
        __syncthreads();
        for (int s = 128; s; s >>= 1) { if (t < s) red[t] += red[t + s]; __syncthreads(); }
        if (t == 0) { rowLoss[i] = red[0]; winner[i] = wsh; }
    } else {
        copy_groups((const f4*)centers, (f4*)outAll, 1, K0E, (b - 512) * TPB + t, 1536 * TPB);
    }
}

// ---- k1: blocks 0-255 pairwise dist (32x32 tiles); blocks 256-2047 copy chunk1 ----
__global__ __launch_bounds__(TPB) void k1_pairdist(
    const float* __restrict__ centers, const float* __restrict__ cgbuf,
    float* __restrict__ dist, float* __restrict__ outAll)
{
    const int b = blockIdx.x, t = threadIdx.x;
    if (b < 256) {
        __shared__ float As[16][33];
        __shared__ float Bs[16][33];
        const int bi = b >> 4, bj = b & 15;
        const int tx = t & 15, ty = t >> 4;
        float a00 = 0.f, a01 = 0.f, a10 = 0.f, a11 = 0.f;
        for (int k0 = 0; k0 < D; k0 += 16) {
            #pragma unroll
            for (int it = 0; it < 2; ++it) {
                int idx = t + it * 256;              // 0..511
                int r = idx >> 4, kk = idx & 15;
                As[kk][r] = cgbuf[(size_t)(bi * 32 + r) * D + k0 + kk];
                Bs[kk][r] = cgbuf[(size_t)(bj * 32 + r) * D + k0 + kk];
            }
            __syncthreads();
            #pragma unroll
            for (int kk = 0; kk < 16; ++kk) {
                float x0 = As[kk][ty * 2], x1 = As[kk][ty * 2 + 1];
                float y0 = Bs[kk][tx * 2], y1 = Bs[kk][tx * 2 + 1];
                float d00 = x0 - y0, d01 = x0 - y1, d10 = x1 - y0, d11 = x1 - y1;
                a00 += d00 * d00; a01 += d01 * d01; a10 += d10 * d10; a11 += d11 * d11;
            }
            __syncthreads();
        }
        int r0 = bi * 32 + ty * 2, c0 = bj * 32 + tx * 2;
        dist[r0 * B + c0]           = sqrtf(a00);
        dist[r0 * B + c0 + 1]       = sqrtf(a01);
        dist[(r0 + 1) * B + c0]     = sqrtf(a10);
        dist[(r0 + 1) * B + c0 + 1] = sqrtf(a11);
    } else {
        copy_groups((const f4*)centers, (f4*)outAll, K0E, K1E, (b - 256) * TPB + t, 1792 * TPB);
    }
}

// ---- k2: blocks 0-511 masked softmax per row; blocks 512-2047 copy chunk2 ----
__global__ __launch_bounds__(TPB) void k2_softmax(
    const float* __restrict__ centers, const float* __restrict__ dist,
    const int* __restrict__ labels, float* __restrict__ Wm,
    float* __restrict__ rowS, float* __restrict__ rowCnt, float* __restrict__ outAll)
{
    const int b = blockIdx.x, t = threadIdx.x;
    if (b < B) {
        __shared__ float red[TPB];
        __shared__ int labs[B];
        labs[t] = labels[t]; labs[t + 256] = labels[t + 256];
        __syncthreads();
        const int i = b;
        const int li = labs[i];
        float d0 = dist[i * B + t], d1 = dist[i * B + t + 256];
        int m0 = (labs[t] != li) && (d0 <= MARGIN);
        int m1 = (labs[t + 256] != li) && (d1 <= MARGIN);
        red[t] = fmaxf(m0 ? d0 : 0.f, m1 ? d1 : 0.f); __syncthreads();
        for (int s = 128; s; s >>= 1) { if (t < s) red[t] = fmaxf(red[t], red[t + s]); __syncthreads(); }
        float maxd = red[0]; __syncthreads();
        float n0 = m0 ? expf(maxd - d0) : 0.f;
        float n1 = m1 ? expf(maxd - d1) : 0.f;
        red[t] = n0 + n1; __syncthreads();
        for (int s = 128; s; s >>= 1) { if (t < s) red[t] += red[t + s]; __syncthreads(); }
        float Z = red[0] + 1e-6f; __syncthreads();
        float invZ = 1.f / Z;
        Wm[i * B + t]       = n0 * invZ;
        Wm[i * B + t + 256] = n1 * invZ;
        red[t] = (float)(m0 + m1); __syncthreads();
        for (int s = 128; s; s >>= 1) { if (t < s) red[t] += red[t + s]; __syncthreads(); }
        if (t == 0) { rowS[i] = (Z - 1e-6f) * invZ; rowCnt[i] = red[0]; }
    } else {
        copy_groups((const f4*)centers, (f4*)outAll, K1E, K2E, (b - 512) * TPB + t, 1536 * TPB);
    }
}

// ---- k3: blocks 0-255 delta2 GEMM -> vals; block 256 loss + head/tail; 257-2047 copy chunk3 ----
__global__ __launch_bounds__(TPB) void k3_gemm(
    const float* __restrict__ features, const float* __restrict__ centers,
    const float* __restrict__ cgbuf, const float* __restrict__ Wm,
    const float* __restrict__ rowS, const float* __restrict__ rowCnt,
    const float* __restrict__ rowLoss, float* __restrict__ vals,
    float* __restrict__ out, float* __restrict__ outAll)
{
    const int b = blockIdx.x, t = threadIdx.x;
    float* outC = out + 1;
    if (b < 256) {
        __shared__ float red[TPB];
        __shared__ float As[16][33];
        __shared__ float Bs[16][33];
        __shared__ float fsh;
        // flag = (sum of all rowCnt >= 1), recomputed per block
        red[t] = rowCnt[t] + rowCnt[t + 256]; __syncthreads();
        for (int s = 128; s; s >>= 1) { if (t < s) red[t] += red[t + s]; __syncthreads(); }
        if (t == 0) fsh = (red[0] < 1.0f) ? 0.f : 1.f;
        __syncthreads();
        const float flagv = fsh;
        const int bi = b >> 4, bj = b & 15;
        const int tx = t & 15, ty = t >> 4;
        float a00 = 0.f, a01 = 0.f, a10 = 0.f, a11 = 0.f;
        for (int j0 = 0; j0 < B; j0 += 16) {
            #pragma unroll
            for (int it = 0; it < 2; ++it) {
                int idx = t + it * 256;
                int r = idx >> 4, jj = idx & 15;
                As[jj][r] = Wm[(size_t)(bi * 32 + r) * B + j0 + jj];
                int c = idx & 31, jj2 = idx >> 5;
                Bs[jj2][c] = cgbuf[(size_t)(j0 + jj2) * D + bj * 32 + c];
            }
            __syncthreads();
            #pragma unroll
            for (int kk = 0; kk < 16; ++kk) {
                float w0 = As[kk][ty * 2], w1 = As[kk][ty * 2 + 1];
                float c0 = Bs[kk][tx * 2], c1 = Bs[kk][tx * 2 + 1];
                a00 += w0 * c0; a01 += w0 * c1; a10 += w1 * c0; a11 += w1 * c1;
            }
            __syncthreads();
        }
        const int i0 = bi * 32 + ty * 2, i1 = i0 + 1;
        const int dcol = bj * 32 + tx * 2;
        float s0 = rowS[i0], s1 = rowS[i1];
        float c, f;
        c = cgbuf[(size_t)i0 * D + dcol];     f = features[(size_t)i0 * D + dcol];
        vals[(size_t)i0 * D + dcol]     = 0.5f * (c + f) - BETA * flagv * (s0 * c - a00);
        c = cgbuf[(size_t)i0 * D + dcol + 1]; f = features[(size_t)i0 * D + dcol + 1];
        vals[(size_t)i0 * D + dcol + 1] = 0.5f * (c + f) - BETA * flagv * (s0 * c - a01);
        c = cgbuf[(size_t)i1 * D + dcol];     f = features[(size_t)i1 * D + dcol];
        vals[(size_t)i1 * D + dcol]     = 0.5f * (c + f) - BETA * flagv * (s1 * c - a10);
        c = cgbuf[(size_t)i1 * D + dcol + 1]; f = features[(size_t)i1 * D + dcol + 1];
        vals[(size_t)i1 * D + dcol + 1] = 0.5f * (c + f) - BETA * flagv * (s1 * c - a11);
    } else if (b == 256) {
        __shared__ float red[TPB];
        red[t] = rowLoss[t] + rowLoss[t + 256]; __syncthreads();
        for (int s = 128; s; s >>= 1) { if (t < s) red[t] += red[t + s]; __syncthreads(); }
        if (t == 0) out[0] = red[0] * (1.0f / ((float)B * (float)D));
        // head (centers[0..2]) and tail (centers[NFLOAT-1]) not covered by the group grid.
        // k4's scatter (next kernel) overwrites these if they belong to winner rows.
        if (t == 1) { outC[0] = centers[0]; outC[1] = centers[1]; outC[2] = centers[2]; }
        if (t == 2) { outC[NFLOAT - 1] = centers[NFLOAT - 1]; }
    } else {
        copy_groups((const f4*)centers, (f4*)outAll, K2E, NG, (b - 257) * TPB + t, 1791 * TPB);
    }
}

// ---- k4: scatter winner rows from vals (runs after ALL copying complete) ----
__global__ __launch_bounds__(TPB) void k4_scatter(
    const float* __restrict__ vals, const int* __restrict__ labels,
    const int* __restrict__ winner, float* __restrict__ outC)
{
    const int b = blockIdx.x, t = threadIdx.x;
    const int i = b * 2 + (t >> 7);          // row 0..511
    const int dcol = (t & 127) * 4;
    if (!winner[i]) return;
    f4 v;
    __builtin_memcpy(&v, &vals[(size_t)i * D + dcol], 16);
    float* dst = outC + (size_t)labels[i] * D + dcol;   // 4B-aligned only
    __builtin_memcpy(dst, &v, 16);
}

extern "C" void kernel_launch(void* const* d_in, const int* in_sizes, int n_in,
                              void* d_out, int out_size, void* d_ws, size_t ws_size,
                              hipStream_t stream)
{
    const float* features = (const float*)d_in[0];
    const int*   labels   = (const int*)d_in[1];
    const float* centers  = (const float*)d_in[2];

    float* out  = (float*)d_out;     // out[0] = loss, out[1..] = new_centers
    float* outC = out + 1;

    char* ws = (char*)d_ws;
    float* cgbuf   = (float*)(ws);                 // 1 MB
    float* dist    = (float*)(ws + 1048576);       // 1 MB
    float* Wm      = (float*)(ws + 2097152);       // 1 MB
    float* vals    = (float*)(ws + 3145728);       // 1 MB
    float* rowLoss = (float*)(ws + 4194304);       // 2 KB
    float* rowS    = (float*)(ws + 4196352);       // 2 KB
    float* rowCnt  = (float*)(ws + 4198400);       // 2 KB
    int*   winner  = (int*)  (ws + 4200448);       // 2 KB

    k0_gather<<<2048, TPB, 0, stream>>>(centers, features, labels, cgbuf, rowLoss, winner, out);
    k1_pairdist<<<2048, TPB, 0, stream>>>(centers, cgbuf, dist, out);
    k2_softmax<<<2048, TPB, 0, stream>>>(centers, dist, labels, Wm, rowS, rowCnt, out);
    k3_gemm<<<2048, TPB, 0, stream>>>(features, centers, cgbuf, Wm, rowS, rowCnt,
                                      rowLoss, vals, out, out);
    k4_scatter<<<256, TPB, 0, stream>>>(vals, labels, winner, outC);
}

// Round 14
// 104.506 us; speedup vs baseline: 1.2145x; 1.2145x over previous
//
#include <hip/hip_runtime.h>

// Problem constants (match reference)
#define B 512
#define D 512
#define NC 100000
#define BETA 0.1f
#define MARGIN 50.0f
#define TPB 256
#define NFLOAT (NC * D)            // 51,200,000 floats in new_centers
// Aligned f4 groups of the OUT buffer: group g = out[4g..4g+4).
// Group 0 holds loss + centers[0..2] (patched scalar); groups [1, NG) are bulk.
// out[4g+0]=centers[4g-1]=src4[g-1].w ; out[4g+1..3]=src4[g].x/.y/.z
#define NG 12800000
// Per-kernel chunk partition of [1, NG), sized by worker capacity (dedicated + 0.7*joiners).
// Each chunk sub-split: dedicated copy blocks take the big part, compute blocks join after
// their compute phase and take the small tail part.
#define A0 1
#define A1 2665601   // k0 dedicated end / k0 joiner start
#define A2 3136001   // k0 end = k1 start
#define A3 6171521   // k1 dedicated end / joiner start
#define A4 6400001   // k1 end = k2 start
#define A5 9065601   // k2 dedicated end / joiner start
#define A6 9536001   // k2 end = k3 start
#define A7 12571521  // k3 dedicated end / joiner start

typedef float f4 __attribute__((ext_vector_type(4)));

// R10-verbatim copy: BOTH sides 16B-aligned; aligned f4 load, shfl_up for the previous
// group's .w (lane 0 patch-loads), aligned NONTEMPORAL f4 store (keeps write stream out
// of L3 so centers stays resident — R13 A/B proved this is worth ~25us).
// Wave-uniform loop bounds: every lane executes every __shfl_up in lockstep.
__device__ __forceinline__ void copy_groups(const f4* __restrict__ src4, f4* __restrict__ dst4,
                                            int lo, int hi, int widx, int wstride)
{
    const int lane = widx & 63;
    int g = lo + widx;
    for (; (g - lane) + 63 + 7 * wstride < hi; g += 8 * wstride) {
        f4 v[8];
        #pragma unroll
        for (int u = 0; u < 8; ++u) v[u] = src4[g + u * wstride];
        float pw[8];
        #pragma unroll
        for (int u = 0; u < 8; ++u) {
            pw[u] = __shfl_up(v[u].w, 1, 64);
            if (lane == 0) pw[u] = src4[g + u * wstride - 1].w;
        }
        #pragma unroll
        for (int u = 0; u < 8; ++u) {
            f4 o = { pw[u], v[u].x, v[u].y, v[u].z };
            __builtin_nontemporal_store(o, dst4 + (g + u * wstride));
        }
    }
    for (; (g - lane) < hi; g += wstride) {
        int gc = (g < hi) ? g : (hi - 1);
        f4 v = src4[gc];
        float pw = __shfl_up(v.w, 1, 64);
        if (lane == 0) pw = src4[gc - 1].w;
        if (g < hi) {
            f4 o = { pw, v.x, v.y, v.z };
            __builtin_nontemporal_store(o, dst4 + g);
        }
    }
}

// ---- k0: blocks 0-511 gather cg + loss + winner THEN join copy; 512-2047 copy chunk0 ----
__global__ __launch_bounds__(TPB) void k0_gather(
    const float* __restrict__ centers, const float* __restrict__ features,
    const int* __restrict__ labels, float* __restrict__ cgbuf,
    float* __restrict__ rowLoss, int* __restrict__ winner, float* __restrict__ outAll)
{
    const int b = blockIdx.x, t = threadIdx.x;
    if (b < B) {
        __shared__ float red[TPB];
        __shared__ int labs[B];
        __shared__ int wsh;
        labs[t] = labels[t]; labs[t + 256] = labels[t + 256];
        if (t == 0) wsh = 1;
        __syncthreads();
        const int i = b;
        const int li = labs[i];
        const float2* crow = (const float2*)(centers + (size_t)li * D);
        const float2* frow = (const float2*)(features + (size_t)i * D);
        float2 c = crow[t], f = frow[t];
        ((float2*)(cgbuf + (size_t)i * D))[t] = c;
        float dx = c.x - f.x, dy = c.y - f.y;
        red[t] = fminf(fmaxf(dx * dx, 1e-12f), 1e12f) + fminf(fmaxf(dy * dy, 1e-12f), 1e12f);
        for (int j = i + 1 + t; j < B; j += TPB)
            if (labs[j] == li) wsh = 0;           // benign race, same value
        __syncthreads();
        for (int s = 128; s; s >>= 1) { if (t < s) red[t] += red[t + s]; __syncthreads(); }
        if (t == 0) { rowLoss[i] = red[0]; winner[i] = wsh; }
        // join the copy: small joiner sub-chunk over the 512 compute blocks
        copy_groups((const f4*)centers, (f4*)outAll, A1, A2, b * TPB + t, 512 * TPB);
    } else {
        copy_groups((const f4*)centers, (f4*)outAll, A0, A1, (b - 512) * TPB + t, 1536 * TPB);
    }
}

// ---- k1: blocks 0-255 pairwise dist THEN join copy; 256-2047 copy chunk1 ----
__global__ __launch_bounds__(TPB) void k1_pairdist(
    const float* __restrict__ centers, const float* __restrict__ cgbuf,
    float* __restrict__ dist, float* __restrict__ outAll)
{
    const int b = blockIdx.x, t = threadIdx.x;
    if (b < 256) {
        __shared__ float As[16][33];
        __shared__ float Bs[16][33];
        const int bi = b >> 4, bj = b & 15;
        const int tx = t & 15, ty = t >> 4;
        float a00 = 0.f, a01 = 0.f, a10 = 0.f, a11 = 0.f;
        for (int k0 = 0; k0 < D; k0 += 16) {
            #pragma unroll
            for (int it = 0; it < 2; ++it) {
                int idx = t + it * 256;              // 0..511
                int r = idx >> 4, kk = idx & 15;
                As[kk][r] = cgbuf[(size_t)(bi * 32 + r) * D + k0 + kk];
                Bs[kk][r] = cgbuf[(size_t)(bj * 32 + r) * D + k0 + kk];
            }
            __syncthreads();
            #pragma unroll
            for (int kk = 0; kk < 16; ++kk) {
                float x0 = As[kk][ty * 2], x1 = As[kk][ty * 2 + 1];
                float y0 = Bs[kk][tx * 2], y1 = Bs[kk][tx * 2 + 1];
                float d00 = x0 - y0, d01 = x0 - y1, d10 = x1 - y0, d11 = x1 - y1;
                a00 += d00 * d00; a01 += d01 * d01; a10 += d10 * d10; a11 += d11 * d11;
            }
            __syncthreads();
        }
        int r0 = bi * 32 + ty * 2, c0 = bj * 32 + tx * 2;
        dist[r0 * B + c0]           = sqrtf(a00);
        dist[r0 * B + c0 + 1]       = sqrtf(a01);
        dist[(r0 + 1) * B + c0]     = sqrtf(a10);
        dist[(r0 + 1) * B + c0 + 1] = sqrtf(a11);
        copy_groups((const f4*)centers, (f4*)outAll, A3, A4, b * TPB + t, 256 * TPB);
    } else {
        copy_groups((const f4*)centers, (f4*)outAll, A2, A3, (b - 256) * TPB + t, 1792 * TPB);
    }
}

// ---- k2: blocks 0-511 masked softmax THEN join copy; 512-2047 copy chunk2 ----
__global__ __launch_bounds__(TPB) void k2_softmax(
    const float* __restrict__ centers, const float* __restrict__ dist,
    const int* __restrict__ labels, float* __restrict__ Wm,
    float* __restrict__ rowS, float* __restrict__ rowCnt, float* __restrict__ outAll)
{
    const int b = blockIdx.x, t = threadIdx.x;
    if (b < B) {
        __shared__ float red[TPB];
        __shared__ int labs[B];
        labs[t] = labels[t]; labs[t + 256] = labels[t + 256];
        __syncthreads();
        const int i = b;
        const int li = labs[i];
        float d0 = dist[i * B + t], d1 = dist[i * B + t + 256];
        int m0 = (labs[t] != li) && (d0 <= MARGIN);
        int m1 = (labs[t + 256] != li) && (d1 <= MARGIN);
        red[t] = fmaxf(m0 ? d0 : 0.f, m1 ? d1 : 0.f); __syncthreads();
        for (int s = 128; s; s >>= 1) { if (t < s) red[t] = fmaxf(red[t], red[t + s]); __syncthreads(); }
        float maxd = red[0]; __syncthreads();
        float n0 = m0 ? expf(maxd - d0) : 0.f;
        float n1 = m1 ? expf(maxd - d1) : 0.f;
        red[t] = n0 + n1; __syncthreads();
        for (int s = 128; s; s >>= 1) { if (t < s) red[t] += red[t + s]; __syncthreads(); }
        float Z = red[0] + 1e-6f; __syncthreads();
        float invZ = 1.f / Z;
        Wm[i * B + t]       = n0 * invZ;
        Wm[i * B + t + 256] = n1 * invZ;
        red[t] = (float)(m0 + m1); __syncthreads();
        for (int s = 128; s; s >>= 1) { if (t < s) red[t] += red[t + s]; __syncthreads(); }
        if (t == 0) { rowS[i] = (Z - 1e-6f) * invZ; rowCnt[i] = red[0]; }
        copy_groups((const f4*)centers, (f4*)outAll, A5, A6, b * TPB + t, 512 * TPB);
    } else {
        copy_groups((const f4*)centers, (f4*)outAll, A4, A5, (b - 512) * TPB + t, 1536 * TPB);
    }
}

// ---- k3: blocks 0-255 delta2 GEMM -> vals THEN join copy; 256 loss+patch; 257+ copy chunk3 ----
__global__ __launch_bounds__(TPB) void k3_gemm(
    const float* __restrict__ features, const float* __restrict__ centers,
    const float* __restrict__ cgbuf, const float* __restrict__ Wm,
    const float* __restrict__ rowS, const float* __restrict__ rowCnt,
    const float* __restrict__ rowLoss, float* __restrict__ vals,
    float* __restrict__ out, float* __restrict__ outAll)
{
    const int b = blockIdx.x, t = threadIdx.x;
    float* outC = out + 1;
    if (b < 256) {
        __shared__ float red[TPB];
        __shared__ float As[16][33];
        __shared__ float Bs[16][33];
        __shared__ float fsh;
        // flag = (sum of all rowCnt >= 1), recomputed per block
        red[t] = rowCnt[t] + rowCnt[t + 256]; __syncthreads();
        for (int s = 128; s; s >>= 1) { if (t < s) red[t] += red[t + s]; __syncthreads(); }
        if (t == 0) fsh = (red[0] < 1.0f) ? 0.f : 1.f;
        __syncthreads();
        const float flagv = fsh;
        const int bi = b >> 4, bj = b & 15;
        const int tx = t & 15, ty = t >> 4;
        float a00 = 0.f, a01 = 0.f, a10 = 0.f, a11 = 0.f;
        for (int j0 = 0; j0 < B; j0 += 16) {
            #pragma unroll
            for (int it = 0; it < 2; ++it) {
                int idx = t + it * 256;
                int r = idx >> 4, jj = idx & 15;
                As[jj][r] = Wm[(size_t)(bi * 32 + r) * B + j0 + jj];
                int c = idx & 31, jj2 = idx >> 5;
                Bs[jj2][c] = cgbuf[(size_t)(j0 + jj2) * D + bj * 32 + c];
            }
            __syncthreads();
            #pragma unroll
            for (int kk = 0; kk < 16; ++kk) {
                float w0 = As[kk][ty * 2], w1 = As[kk][ty * 2 + 1];
                float c0 = Bs[kk][tx * 2], c1 = Bs[kk][tx * 2 + 1];
                a00 += w0 * c0; a01 += w0 * c1; a10 += w1 * c0; a11 += w1 * c1;
            }
            __syncthreads();
        }
        const int i0 = bi * 32 + ty * 2, i1 = i0 + 1;
        const int dcol = bj * 32 + tx * 2;
        float s0 = rowS[i0], s1 = rowS[i1];
        float c, f;
        c = cgbuf[(size_t)i0 * D + dcol];     f = features[(size_t)i0 * D + dcol];
        vals[(size_t)i0 * D + dcol]     = 0.5f * (c + f) - BETA * flagv * (s0 * c - a00);
        c = cgbuf[(size_t)i0 * D + dcol + 1]; f = features[(size_t)i0 * D + dcol + 1];
        vals[(size_t)i0 * D + dcol + 1] = 0.5f * (c + f) - BETA * flagv * (s0 * c - a01);
        c = cgbuf[(size_t)i1 * D + dcol];     f = features[(size_t)i1 * D + dcol];
        vals[(size_t)i1 * D + dcol]     = 0.5f * (c + f) - BETA * flagv * (s1 * c - a10);
        c = cgbuf[(size_t)i1 * D + dcol + 1]; f = features[(size_t)i1 * D + dcol + 1];
        vals[(size_t)i1 * D + dcol + 1] = 0.5f * (c + f) - BETA * flagv * (s1 * c - a11);
        copy_groups((const f4*)centers, (f4*)outAll, A7, NG, b * TPB + t, 256 * TPB);
    } else if (b == 256) {
        __shared__ float red[TPB];
        red[t] = rowLoss[t] + rowLoss[t + 256]; __syncthreads();
        for (int s = 128; s; s >>= 1) { if (t < s) red[t] += red[t + s]; __syncthreads(); }
        if (t == 0) out[0] = red[0] * (1.0f / ((float)B * (float)D));
        // head (centers[0..2]) and tail (centers[NFLOAT-1]) not covered by the group grid.
        // k4's scatter (next kernel) overwrites these if they belong to winner rows.
        if (t == 1) { outC[0] = centers[0]; outC[1] = centers[1]; outC[2] = centers[2]; }
        if (t == 2) { outC[NFLOAT - 1] = centers[NFLOAT - 1]; }
    } else {
        copy_groups((const f4*)centers, (f4*)outAll, A6, A7, (b - 257) * TPB + t, 1791 * TPB);
    }
}

// ---- k4: scatter winner rows from vals (runs after ALL copying complete) ----
__global__ __launch_bounds__(TPB) void k4_scatter(
    const float* __restrict__ vals, const int* __restrict__ labels,
    const int* __restrict__ winner, float* __restrict__ outC)
{
    const int b = blockIdx.x, t = threadIdx.x;
    const int i = b * 2 + (t >> 7);          // row 0..511
    const int dcol = (t & 127) * 4;
    if (!winner[i]) return;
    f4 v;
    __builtin_memcpy(&v, &vals[(size_t)i * D + dcol], 16);
    float* dst = outC + (size_t)labels[i] * D + dcol;   // 4B-aligned only
    __builtin_memcpy(dst, &v, 16);
}

extern "C" void kernel_launch(void* const* d_in, const int* in_sizes, int n_in,
                              void* d_out, int out_size, void* d_ws, size_t ws_size,
                              hipStream_t stream)
{
    const float* features = (const float*)d_in[0];
    const int*   labels   = (const int*)d_in[1];
    const float* centers  = (const float*)d_in[2];

    float* out  = (float*)d_out;     // out[0] = loss, out[1..] = new_centers
    float* outC = out + 1;

    char* ws = (char*)d_ws;
    float* cgbuf   = (float*)(ws);                 // 1 MB
    float* dist    = (float*)(ws + 1048576);       // 1 MB
    float* Wm      = (float*)(ws + 2097152);       // 1 MB
    float* vals    = (float*)(ws + 3145728);       // 1 MB
    float* rowLoss = (float*)(ws + 4194304);       // 2 KB
    float* rowS    = (float*)(ws + 4196352);       // 2 KB
    float* rowCnt  = (float*)(ws + 4198400);       // 2 KB
    int*   winner  = (int*)  (ws + 4200448);       // 2 KB

    k0_gather<<<2048, TPB, 0, stream>>>(centers, features, labels, cgbuf, rowLoss, winner, out);
    k1_pairdist<<<2048, TPB, 0, stream>>>(centers, cgbuf, dist, out);
    k2_softmax<<<2048, TPB, 0, stream>>>(centers, dist, labels, Wm, rowS, rowCnt, out);
    k3_gemm<<<2048, TPB, 0, stream>>>(features, centers, cgbuf, Wm, rowS, rowCnt,
                                      rowLoss, vals, out, out);
    k4_scatter<<<256, TPB, 0, stream>>>(vals, labels, winner, outC);
}

// Round 15
// 101.819 us; speedup vs baseline: 1.2465x; 1.0264x over previous
//
#include <hip/hip_runtime.h>

// Problem constants (match reference)
#define B 512
#define D 512
#define NC 100000
#define BETA 0.1f
#define MARGIN 50.0f
#define TPB 256
#define NFLOAT (NC * D)            // 51,200,000 floats in new_centers
// Aligned f4 groups of the OUT buffer: group g = out[4g..4g+4).
// Group 0 holds loss + centers[0..2] (patched scalar); groups [1, NG) are bulk.
// out[4g+0]=centers[4g-1]=src4[g-1].w ; out[4g+1..3]=src4[g].x/.y/.z
#define NG 12800000
// chunk boundaries over groups [1, NG), ~proportional to copy-worker counts 1536/1792/1536/1791
#define K0E 2954330
#define K1E 6401047
#define K2E 9355376

typedef float f4 __attribute__((ext_vector_type(4)));

// Copy out-groups [lo,hi): BOTH sides 16B-aligned. Each lane: 1 aligned f4 load,
// shfl_up for the previous group's .w (lane 0 patch-loads), aligned nt f4 store.
// ALL loop conditions are wave-uniform (g - lane is wave-invariant), so every lane
// executes every __shfl_up in lockstep; only loads are clamped / stores predicated.
// NT stores are essential (R13 A/B: +25us without) — they keep the 205MB write
// stream out of L2/L3 so `centers` stays L3-resident (FETCH ~110MB not ~205MB).
__device__ __forceinline__ void copy_groups(const f4* __restrict__ src4, f4* __restrict__ dst4,
                                            int lo, int hi, int widx, int wstride)
{
    const int lane = widx & 63;
    int g = lo + widx;
    // main: lane63's 8th group still < hi  ->  no predication needed anywhere
    for (; (g - lane) + 63 + 7 * wstride < hi; g += 8 * wstride) {
        f4 v[8];
        #pragma unroll
        for (int u = 0; u < 8; ++u) v[u] = src4[g + u * wstride];
        float pw[8];
        #pragma unroll
        for (int u = 0; u < 8; ++u) {
            pw[u] = __shfl_up(v[u].w, 1, 64);
            if (lane == 0) pw[u] = src4[g + u * wstride - 1].w;
        }
        #pragma unroll
        for (int u = 0; u < 8; ++u) {
            f4 o = { pw[u], v[u].x, v[u].y, v[u].z };
            __builtin_nontemporal_store(o, dst4 + (g + u * wstride));
        }
    }
    // tail: uniform condition on lane0's g (max remaining); clamp loads, predicate stores
    for (; (g - lane) < hi; g += wstride) {
        int gc = (g < hi) ? g : (hi - 1);
        f4 v = src4[gc];
        float pw = __shfl_up(v.w, 1, 64);
        if (lane == 0) pw = src4[gc - 1].w;
        if (g < hi) {
            f4 o = { pw, v.x, v.y, v.z };
            __builtin_nontemporal_store(o, dst4 + g);
        }
    }
}

// ---- k0: blocks 0-511 gather cg + loss partial + winner; blocks 512-2047 copy chunk0 ----
__global__ __launch_bounds__(TPB) void k0_gather(
    const float* __restrict__ centers, const float* __restrict__ features,
    const int* __restrict__ labels, float* __restrict__ cgbuf,
    float* __restrict__ rowLoss, int* __restrict__ winner, float* __restrict__ outAll)
{
    const int b = blockIdx.x, t = threadIdx.x;
    if (b < B) {
        __shared__ float red[TPB];
        __shared__ int labs[B];
        __shared__ int wsh;
        labs[t] = labels[t]; labs[t + 256] = labels[t + 256];
        if (t == 0) wsh = 1;
        __syncthreads();
        const int i = b;
        const int li = labs[i];
        const float2* crow = (const float2*)(centers + (size_t)li * D);
        const float2* frow = (const float2*)(features + (size_t)i * D);
        float2 c = crow[t], f = frow[t];
        ((float2*)(cgbuf + (size_t)i * D))[t] = c;
        float dx = c.x - f.x, dy = c.y - f.y;
        red[t] = fminf(fmaxf(dx * dx, 1e-12f), 1e12f) + fminf(fmaxf(dy * dy, 1e-12f), 1e12f);
        for (int j = i + 1 + t; j < B; j += TPB)
            if (labs[j] == li) wsh = 0;           // benign race, same value
        __syncthreads();
        for (int s = 128; s; s >>= 1) { if (t < s) red[t] += red[t + s]; __syncthreads(); }
        if (t == 0) { rowLoss[i] = red[0]; winner[i] = wsh; }
    } else {
        copy_groups((const f4*)centers, (f4*)outAll, 1, K0E, (b - 512) * TPB + t, 1536 * TPB);
    }
}

// ---- k1: blocks 0-255 pairwise dist (32x32 tiles); blocks 256-2047 copy chunk1 ----
__global__ __launch_bounds__(TPB) void k1_pairdist(
    const float* __restrict__ centers, const float* __restrict__ cgbuf,
    float* __restrict__ dist, float* __restrict__ outAll)
{
    const int b = blockIdx.x, t = threadIdx.x;
    if (b < 256) {
        __shared__ float As[16][33];
        __shared__ float Bs[16][33];
        const int bi = b >> 4, bj = b & 15;
        const int tx = t & 15, ty = t >> 4;
        float a00 = 0.f, a01 = 0.f, a10 = 0.f, a11 = 0.f;
        for (int k0 = 0; k0 < D; k0 += 16) {
            #pragma unroll
            for (int it = 0; it < 2; ++it) {
                int idx = t + it * 256;              // 0..511
                int r = idx >> 4, kk = idx & 15;
                As[kk][r] = cgbuf[(size_t)(bi * 32 + r) * D + k0 + kk];
                Bs[kk][r] = cgbuf[(size_t)(bj * 32 + r) * D + k0 + kk];
            }
            __syncthreads();
            #pragma unroll
            for (int kk = 0; kk < 16; ++kk) {
                float x0 = As[kk][ty * 2], x1 = As[kk][ty * 2 + 1];
                float y0 = Bs[kk][tx * 2], y1 = Bs[kk][tx * 2 + 1];
                float d00 = x0 - y0, d01 = x0 - y1, d10 = x1 - y0, d11 = x1 - y1;
                a00 += d00 * d00; a01 += d01 * d01; a10 += d10 * d10; a11 += d11 * d11;
            }
            __syncthreads();
        }
        int r0 = bi * 32 + ty * 2, c0 = bj * 32 + tx * 2;
        dist[r0 * B + c0]           = sqrtf(a00);
        dist[r0 * B + c0 + 1]       = sqrtf(a01);
        dist[(r0 + 1) * B + c0]     = sqrtf(a10);
        dist[(r0 + 1) * B + c0 + 1] = sqrtf(a11);
    } else {
        copy_groups((const f4*)centers, (f4*)outAll, K0E, K1E, (b - 256) * TPB + t, 1792 * TPB);
    }
}

// ---- k2: blocks 0-511 masked softmax per row; blocks 512-2047 copy chunk2 ----
__global__ __launch_bounds__(TPB) void k2_softmax(
    const float* __restrict__ centers, const float* __restrict__ dist,
    const int* __restrict__ labels, float* __restrict__ Wm,
    float* __restrict__ rowS, float* __restrict__ rowCnt, float* __restrict__ outAll)
{
    const int b = blockIdx.x, t = threadIdx.x;
    if (b < B) {
        __shared__ float red[TPB];
        __shared__ int labs[B];
        labs[t] = labels[t]; labs[t + 256] = labels[t + 256];
        __syncthreads();
        const int i = b;
        const int li = labs[i];
        float d0 = dist[i * B + t], d1 = dist[i * B + t + 256];
        int m0 = (labs[t] != li) && (d0 <= MARGIN);
        int m1 = (labs[t + 256] != li) && (d1 <= MARGIN);
        red[t] = fmaxf(m0 ? d0 : 0.f, m1 ? d1 : 0.f); __syncthreads();
        for (int s = 128; s; s >>= 1) { if (t < s) red[t] = fmaxf(red[t], red[t + s]); __syncthreads(); }
        float maxd = red[0]; __syncthreads();
        float n0 = m0 ? expf(maxd - d0) : 0.f;
        float n1 = m1 ? expf(maxd - d1) : 0.f;
        red[t] = n0 + n1; __syncthreads();
        for (int s = 128; s; s >>= 1) { if (t < s) red[t] += red[t + s]; __syncthreads(); }
        float Z = red[0] + 1e-6f; __syncthreads();
        float invZ = 1.f / Z;
        Wm[i * B + t]       = n0 * invZ;
        Wm[i * B + t + 256] = n1 * invZ;
        red[t] = (float)(m0 + m1); __syncthreads();
        for (int s = 128; s; s >>= 1) { if (t < s) red[t] += red[t + s]; __syncthreads(); }
        if (t == 0) { rowS[i] = (Z - 1e-6f) * invZ; rowCnt[i] = red[0]; }
    } else {
        copy_groups((const f4*)centers, (f4*)outAll, K1E, K2E, (b - 512) * TPB + t, 1536 * TPB);
    }
}

// ---- k3: blocks 0-255 delta2 GEMM -> vals; block 256 loss + head/tail; 257-2047 copy chunk3 ----
__global__ __launch_bounds__(TPB) void k3_gemm(
    const float* __restrict__ features, const float* __restrict__ centers,
    const float* __restrict__ cgbuf, const float* __restrict__ Wm,
    const float* __restrict__ rowS, const float* __restrict__ rowCnt,
    const float* __restrict__ rowLoss, float* __restrict__ vals,
    float* __restrict__ out, float* __restrict__ outAll)
{
    const int b = blockIdx.x, t = threadIdx.x;
    float* outC = out + 1;
    if (b < 256) {
        __shared__ float red[TPB];
        __shared__ float As[16][33];
        __shared__ float Bs[16][33];
        __shared__ float fsh;
        // flag = (sum of all rowCnt >= 1), recomputed per block
        red[t] = rowCnt[t] + rowCnt[t + 256]; __syncthreads();
        for (int s = 128; s; s >>= 1) { if (t < s) red[t] += red[t + s]; __syncthreads(); }
        if (t == 0) fsh = (red[0] < 1.0f) ? 0.f : 1.f;
        __syncthreads();
        const float flagv = fsh;
        const int bi = b >> 4, bj = b & 15;
        const int tx = t & 15, ty = t >> 4;
        float a00 = 0.f, a01 = 0.f, a10 = 0.f, a11 = 0.f;
        for (int j0 = 0; j0 < B; j0 += 16) {
            #pragma unroll
            for (int it = 0; it < 2; ++it) {
                int idx = t + it * 256;
                int r = idx >> 4, jj = idx & 15;
                As[jj][r] = Wm[(size_t)(bi * 32 + r) * B + j0 + jj];
                int c = idx & 31, jj2 = idx >> 5;
                Bs[jj2][c] = cgbuf[(size_t)(j0 + jj2) * D + bj * 32 + c];
            }
            __syncthreads();
            #pragma unroll
            for (int kk = 0; kk < 16; ++kk) {
                float w0 = As[kk][ty * 2], w1 = As[kk][ty * 2 + 1];
                float c0 = Bs[kk][tx * 2], c1 = Bs[kk][tx * 2 + 1];
                a00 += w0 * c0; a01 += w0 * c1; a10 += w1 * c0; a11 += w1 * c1;
            }
            __syncthreads();
        }
        const int i0 = bi * 32 + ty * 2, i1 = i0 + 1;
        const int dcol = bj * 32 + tx * 2;
        float s0 = rowS[i0], s1 = rowS[i1];
        float c, f;
        c = cgbuf[(size_t)i0 * D + dcol];     f = features[(size_t)i0 * D + dcol];
        vals[(size_t)i0 * D + dcol]     = 0.5f * (c + f) - BETA * flagv * (s0 * c - a00);
        c = cgbuf[(size_t)i0 * D + dcol + 1]; f = features[(size_t)i0 * D + dcol + 1];
        vals[(size_t)i0 * D + dcol + 1] = 0.5f * (c + f) - BETA * flagv * (s0 * c - a01);
        c = cgbuf[(size_t)i1 * D + dcol];     f = features[(size_t)i1 * D + dcol];
        vals[(size_t)i1 * D + dcol]     = 0.5f * (c + f) - BETA * flagv * (s1 * c - a10);
        c = cgbuf[(size_t)i1 * D + dcol + 1]; f = features[(size_t)i1 * D + dcol + 1];
        vals[(size_t)i1 * D + dcol + 1] = 0.5f * (c + f) - BETA * flagv * (s1 * c - a11);
    } else if (b == 256) {
        __shared__ float red[TPB];
        red[t] = rowLoss[t] + rowLoss[t + 256]; __syncthreads();
        for (int s = 128; s; s >>= 1) { if (t < s) red[t] += red[t + s]; __syncthreads(); }
        if (t == 0) out[0] = red[0] * (1.0f / ((float)B * (float)D));
        // head (centers[0..2]) and tail (centers[NFLOAT-1]) not covered by the group grid.
        // k4's scatter (next kernel) overwrites these if they belong to winner rows.
        if (t == 1) { outC[0] = centers[0]; outC[1] = centers[1]; outC[2] = centers[2]; }
        if (t == 2) { outC[NFLOAT - 1] = centers[NFLOAT - 1]; }
    } else {
        copy_groups((const f4*)centers, (f4*)outAll, K2E, NG, (b - 257) * TPB + t, 1791 * TPB);
    }
}

// ---- k4: scatter winner rows from vals (runs after ALL copying complete) ----
__global__ __launch_bounds__(TPB) void k4_scatter(
    const float* __restrict__ vals, const int* __restrict__ labels,
    const int* __restrict__ winner, float* __restrict__ outC)
{
    const int b = blockIdx.x, t = threadIdx.x;
    const int i = b * 2 + (t >> 7);          // row 0..511
    const int dcol = (t & 127) * 4;
    if (!winner[i]) return;
    f4 v;
    __builtin_memcpy(&v, &vals[(size_t)i * D + dcol], 16);
    float* dst = outC + (size_t)labels[i] * D + dcol;   // 4B-aligned only
    __builtin_memcpy(dst, &v, 16);
}

extern "C" void kernel_launch(void* const* d_in, const int* in_sizes, int n_in,
                              void* d_out, int out_size, void* d_ws, size_t ws_size,
                              hipStream_t stream)
{
    const float* features = (const float*)d_in[0];
    const int*   labels   = (const int*)d_in[1];
    const float* centers  = (const float*)d_in[2];

    float* out  = (float*)d_out;     // out[0] = loss, out[1..] = new_centers
    float* outC = out + 1;

    char* ws = (char*)d_ws;
    float* cgbuf   = (float*)(ws);                 // 1 MB
    float* dist    = (float*)(ws + 1048576);       // 1 MB
    float* Wm      = (float*)(ws + 2097152);       // 1 MB
    float* vals    = (float*)(ws + 3145728);       // 1 MB
    float* rowLoss = (float*)(ws + 4194304);       // 2 KB
    float* rowS    = (float*)(ws + 4196352);       // 2 KB
    float* rowCnt  = (float*)(ws + 4198400);       // 2 KB
    int*   winner  = (int*)  (ws + 4200448);       // 2 KB

    k0_gather<<<2048, TPB, 0, stream>>>(centers, features, labels, cgbuf, rowLoss, winner, out);
    k1_pairdist<<<2048, TPB, 0, stream>>>(centers, cgbuf, dist, out);
    k2_softmax<<<2048, TPB, 0, stream>>>(centers, dist, labels, Wm, rowS, rowCnt, out);
    k3_gemm<<<2048, TPB, 0, stream>>>(features, centers, cgbuf, Wm, rowS, rowCnt,
                                      rowLoss, vals, out, out);
    k4_scatter<<<256, TPB, 0, stream>>>(vals, labels, winner, outC);
}